// Round 4
// baseline (453.278 us; speedup 1.0000x reference)
//
#include <hip/hip_runtime.h>
#include <math.h>

#define H 256
#define W 256
#define NB 8
#define CIN 64
#define COUT 128
#define HW (H * W)
#define TROWS 34
#define TCOLS 40
#define TFLOATS (TROWS * TCOLS)  // 1360 floats per tile
#define TF4 (TFLOATS / 4)        // 340 float4 slots

typedef float f4v __attribute__((ext_vector_type(4)));

// ---------------------------------------------------------------------------
// kfused: offset conv + tanh + cumsum -> ynew  (z = 0..7), kpmat at z == 8.
//
// Channel-split waves: each of 4 waves owns 16 input channels and stages a
// block-wide 34x40 halo tile for ITS channel into a wave-private double
// buffer (no per-channel barriers). Each wave computes the full 32x32x3k
// partial sum in 48 VGPRs (lane owns 4 rows x 4 cols). Per-channel compute
// is ~430 FMA/lane, so the 2-deep register prefetch spans ~2200 cycles --
// covers ~900-cycle HBM latency even at 2 waves/SIMD (512 blocks = 2/CU).
// Cross-wave reduce via LDS once at the end (2 barriers/block total).
// Fetch: 34x40/1024 = 1.33x halo -> ~178 MB total.
// ---------------------------------------------------------------------------
__global__ __launch_bounds__(256, 2) void kfused(const float* __restrict__ x,
                                                 const float* __restrict__ offw,
                                                 const float* __restrict__ convw,
                                                 float* __restrict__ ynew,
                                                 float* __restrict__ P) {
    __shared__ float smem[12288];  // 48 KB: tiles (4w x 2buf x 1360 = 10880) then acc dump (4x48x64 = 12288)

    if (blockIdx.z == NB) {
        // ---- kpmat: P[n][co][t], t = r*4+y (padded stride 16) ----
        float* xl = smem;              // 256 floats
        float* wl = smem + 256;        // 3072 floats
        const int n = blockIdx.y;
        const int co0 = blockIdx.x * 16;
        const int tid = threadIdx.x;
        {
            int ci = tid >> 2, y = tid & 3;
            xl[tid] = x[(((size_t)n * CIN + ci) * H + y) * W];
        }
        for (int p = tid; p < 16 * 192; p += 256) wl[p] = convw[co0 * 192 + p];
        __syncthreads();
        if (tid < 192) {
            int co = tid / 12, t = tid - co * 12;
            int r = t >> 2, y = t & 3;
            float s = 0.f;
#pragma unroll
            for (int ci = 0; ci < CIN; ++ci) s += wl[co * 192 + ci * 3 + r] * xl[ci * 4 + y];
            P[((size_t)n * COUT + co0 + co) * 16 + t] = s;
        }
        return;
    }

    // ---- offset conv ----
    const int n = blockIdx.z;
    const int i0 = blockIdx.y * 32;
    const int j0 = blockIdx.x * 32;
    const int tid = threadIdx.x;
    const int wv = tid >> 6;
    const int lane = tid & 63;
    const int rg = lane >> 3;  // row group: lane owns output rows 4rg..4rg+3
    const int q = lane & 7;    // col quad: cols 4q..4q+3

    float* t0 = smem + wv * (2 * TFLOATS);
    float* t1 = t0 + TFLOATS;

    // per-slot staging constants (channel-independent):
    // slot s = lane + 64*m -> tile row a = s/10, col quad c4 = s%10
    // tile row 0 = global row i0-1; tile col 0 = global col j0-4
    int offs[6];
    bool vms[6];
#pragma unroll
    for (int m = 0; m < 6; ++m) {
        int s = lane + (m << 6);
        int a = s / 10, c4 = s - a * 10;
        int gi = i0 - 1 + a;
        int gj = j0 - 4 + (c4 << 2);
        bool v = (s < TF4) && ((unsigned)gi < (unsigned)H) && ((unsigned)gj < (unsigned)W);
        vms[m] = v;
        offs[m] = v ? (gi * W + gj) : 0;
    }

    const float4 zf4 = make_float4(0.f, 0.f, 0.f, 0.f);
    float acc[4][3][4];
#pragma unroll
    for (int ri = 0; ri < 4; ++ri)
#pragma unroll
        for (int k = 0; k < 3; ++k)
#pragma unroll
            for (int d = 0; d < 4; ++d) acc[ri][k][d] = 0.f;

#define LOADC(cptr, R)                                                      \
    _Pragma("unroll") for (int m = 0; m < 6; ++m)                           \
        R[m] = vms[m] ? *(const float4*)((cptr) + offs[m]) : zf4;

#define STAGE(buf, R)                                                       \
    _Pragma("unroll") for (int m = 0; m < 6; ++m)                           \
        if (m < 5 || lane < (TF4 - 320))                                    \
            *(float4*)((buf) + ((lane + (m << 6)) << 2)) = R[m];

    // per channel: loop 6 tap rows; tap row t contributes to output rows
    // ri in [max(0,t-2), min(3,t)] with kernel row u = t - ri.
#define COMPCH(buf, wp)                                                     \
    {                                                                       \
        _Pragma("unroll") for (int t = 0; t < 6; ++t) {                     \
            const float* rp = (buf) + (4 * rg + t) * TCOLS + 4 * q;         \
            float4 b0 = *(const float4*)(rp);                               \
            float4 b1 = *(const float4*)(rp + 4);                           \
            float4 b2 = *(const float4*)(rp + 8);                           \
            const float r0 = b0.w, r1 = b1.x, r2 = b1.y, r3 = b1.z,         \
                        r4 = b1.w, r5 = b2.x;                               \
            _Pragma("unroll") for (int ri = 0; ri < 4; ++ri) {              \
                if (ri < ((t - 2 > 0) ? t - 2 : 0) || ri > ((t < 3) ? t : 3)) continue; \
                const int u = t - ri;                                       \
                _Pragma("unroll") for (int k = 0; k < 3; ++k) {             \
                    const float w0 = (wp)[k * 576 + u * 3 + 0];             \
                    const float w1 = (wp)[k * 576 + u * 3 + 1];             \
                    const float w2 = (wp)[k * 576 + u * 3 + 2];             \
                    acc[ri][k][0] += r0 * w0 + r1 * w1 + r2 * w2;           \
                    acc[ri][k][1] += r1 * w0 + r2 * w1 + r3 * w2;           \
                    acc[ri][k][2] += r2 * w0 + r3 * w1 + r4 * w2;           \
                    acc[ri][k][3] += r3 * w0 + r4 * w1 + r5 * w2;           \
                }                                                           \
            }                                                               \
        }                                                                   \
    }

    const int c0 = wv << 4;  // this wave's first channel
    const float* xw = x + ((size_t)n * CIN + c0) * HW;
    const float* wp0 = offw + (size_t)c0 * 9;  // offw[k][ci][u][v], k stride 576

    float4 RA[6], RB[6];
    LOADC(xw, RA);
    LOADC(xw + HW, RB);

    for (int cc = 0; cc < 16; cc += 2) {
        STAGE(t0, RA);
        if (cc + 2 < 16) {
            const float* xp = xw + (size_t)(cc + 2) * HW;
            LOADC(xp, RA);
        }
        COMPCH(t0, wp0 + (size_t)cc * 9);
        STAGE(t1, RB);
        if (cc + 3 < 16) {
            const float* xp = xw + (size_t)(cc + 3) * HW;
            LOADC(xp, RB);
        }
        COMPCH(t1, wp0 + (size_t)(cc + 1) * 9);
    }
#undef LOADC
#undef STAGE
#undef COMPCH

    // ---- cross-wave reduce: dump 48 partials per lane, sum over 4 waves ----
    __syncthreads();  // all waves done reading their tiles (accdump aliases them)
#pragma unroll
    for (int ri = 0; ri < 4; ++ri)
#pragma unroll
        for (int k = 0; k < 3; ++k)
#pragma unroll
            for (int d = 0; d < 4; ++d)
                smem[((wv * 48 + ri * 12 + k * 4 + d) << 6) + lane] = acc[ri][k][d];
    __syncthreads();

    // thread tid -> output row = tid>>3 (0..31), col quad q2 = tid&7
    const int row = tid >> 3;
    const int q2 = tid & 7;
    const int srcl = ((row >> 2) << 3) | q2;  // owning lane
    const int rbase = (row & 3) * 12;         // owning reg block

    float y0[4], y1[4], y2[4];
#pragma unroll
    for (int d = 0; d < 4; ++d) {
        float s0 = 0.f, s1 = 0.f, s2 = 0.f;
#pragma unroll
        for (int w = 0; w < 4; ++w) {
            const float* bp = smem + ((w * 48 + rbase) << 6) + srcl;
            s0 += bp[(0 * 4 + d) << 6];
            s1 += bp[(1 * 4 + d) << 6];
            s2 += bp[(2 * 4 + d) << 6];
        }
        float v0 = tanhf(s0), v1 = tanhf(s1), v2 = tanhf(s2);
        y0[d] = v0 + v1;
        y1[d] = v1;
        y2[d] = v1 + v2;
    }
    size_t base = (size_t)n * 3 * HW + (size_t)(i0 + row) * W + (j0 + (q2 << 2));
    *(float4*)(ynew + base) = make_float4(y0[0], y0[1], y0[2], y0[3]);
    *(float4*)(ynew + base + (size_t)HW) = make_float4(y1[0], y1[1], y1[2], y1[3]);
    *(float4*)(ynew + base + (size_t)2 * HW) = make_float4(y2[0], y2[1], y2[2], y2[3]);
}

// ---------------------------------------------------------------------------
// Kernel C: out[n,co,i,j] = sum_t C[t](n,i,j) * P[n,co,t]  (unchanged, verified)
// ---------------------------------------------------------------------------
__global__ __launch_bounds__(256) void kout(const float* __restrict__ ynew,
                                            const float* __restrict__ P,
                                            float* __restrict__ out) {
    __shared__ float Cs[12 * 256];
    __shared__ float Pl[128 * 16];
    const int n = blockIdx.y;
    const int i = blockIdx.x;
    const int tid = threadIdx.x;

    {
        const f4v* src = (const f4v*)(P + (size_t)n * COUT * 16);
        f4v* dst = (f4v*)Pl;
        dst[tid] = src[tid];
        dst[tid + 256] = src[tid + 256];
    }

    {
        const int j = tid;
        float c[12];
#pragma unroll
        for (int t = 0; t < 12; ++t) c[t] = 0.f;
#pragma unroll
        for (int r = 0; r < 3; ++r) {
            int rowi = 3 * i + r;
            int k = rowi >> 8;
            int i2 = rowi & 255;
            float g = (float)(((k + i2 + j) % 3) - 1) +
                      ynew[((size_t)n * 3 + k) * (H * W) + i2 * W + j];
            float gy = g / 127.5f - 1.0f;
            float iy = ((gy + 1.0f) * 256.0f - 1.0f) * 0.5f;
            float fy = floorf(iy);
            int y0 = (int)fy;
            float w1 = iy - fy;
            if ((unsigned)y0 < 4u) c[r * 4 + y0] += 0.5f * (1.0f - w1);
            int y1 = y0 + 1;
            if ((unsigned)y1 < 4u) c[r * 4 + y1] += 0.5f * w1;
        }
#pragma unroll
        for (int t = 0; t < 12; ++t) Cs[t * 256 + j] = c[t];
    }
    __syncthreads();

    const int jq = (tid & 63) * 4;
    const int cg = tid >> 6;
    float4 cc[12];
#pragma unroll
    for (int t = 0; t < 12; ++t) cc[t] = *(const float4*)&Cs[t * 256 + jq];

    float* op = out + (((size_t)n * COUT) * H + i) * W;
    for (int co = cg * 32; co < cg * 32 + 32; ++co) {
        const float4* pp = (const float4*)&Pl[co * 16];
        float4 P0 = pp[0], P1 = pp[1], P2 = pp[2];
        float pv[12] = {P0.x, P0.y, P0.z, P0.w, P1.x, P1.y, P1.z, P1.w,
                        P2.x, P2.y, P2.z, P2.w};
        f4v a = {0.f, 0.f, 0.f, 0.f};
#pragma unroll
        for (int t = 0; t < 12; ++t) {
            a.x += pv[t] * cc[t].x;
            a.y += pv[t] * cc[t].y;
            a.z += pv[t] * cc[t].z;
            a.w += pv[t] * cc[t].w;
        }
        __builtin_nontemporal_store(a, (f4v*)(op + (size_t)co * (H * W) + jq));
    }
}

// ---------------------------------------------------------------------------
extern "C" void kernel_launch(void* const* d_in, const int* in_sizes, int n_in,
                              void* d_out, int out_size, void* d_ws, size_t ws_size,
                              hipStream_t stream) {
    const float* x = (const float*)d_in[0];      // [8,64,256,256]
    const float* offw = (const float*)d_in[1];   // [6,64,3,3]
    const float* convw = (const float*)d_in[2];  // [128,64,3,1]
    float* out = (float*)d_out;                  // [8,128,256,256]

    float* ynew = (float*)d_ws;                  // [8][3][256][256]
    float* P = ynew + (size_t)NB * 3 * HW;       // [8][128][16]

    kfused<<<dim3(8, 8, NB + 1), 256, 0, stream>>>(x, offw, convw, ynew, P);
    kout<<<dim3(H, NB), 256, 0, stream>>>(ynew, P, out);
}

// Round 7
// 402.051 us; speedup vs baseline: 1.1274x; 1.1274x over previous
//
#include <hip/hip_runtime.h>
#include <math.h>

#define H 256
#define W 256
#define NB 8
#define CIN 64
#define COUT 128
#define HW (H * W)

// offset-conv tiling: 8 output rows x 128 output cols per block
#define TR 8
#define TC 128
#define TRH 10        // tile rows incl. vertical halo
#define TCS 34        // tile col slots (float4): words j0-4 .. j0+131
#define RSTRIDE 140   // padded row stride in words (35 slots; 140%32=12 skews banks)
#define TILEW (TRH * RSTRIDE)        // 1400 words per channel tile
#define CPB 4                        // channels per barrier period
#define SLOTS_PER (TRH * TCS)        // 340 slots per channel tile
#define SLOTS_GRP (CPB * SLOTS_PER)  // 1360 slots per period

typedef float f4v __attribute__((ext_vector_type(4)));

// ---------------------------------------------------------------------------
// kfused: offset conv + tanh + cumsum -> ynew (z = 0..7); kpmat at z == 8.
//
// Pipeline per 4-channel period (16 periods):
//   STAGE bufB <- RA (ds_write, consumes all outstanding loads)
//   __syncthreads()            // vmcnt==0 here BY CONSTRUCTION -> no drain stall
//   issue RA <- next 4 channels  (flies during compute, ~1100cy > 900cy HBM lat)
//   COMPUTE bufB (4 channels)
// This removes the barrier-drain-kills-prefetch structure of rounds 0/4.
// ---------------------------------------------------------------------------
__global__ __launch_bounds__(256) void kfused(const float* __restrict__ x,
                                              const float* __restrict__ offw,
                                              const float* __restrict__ convw,
                                              float* __restrict__ ynew,
                                              float* __restrict__ P) {
    __shared__ float smem[2 * CPB * TILEW];  // 44.8 KB

    if (blockIdx.z == NB) {
        // ---- kpmat: P[n][co][t], t = r*4+y (padded stride 16); 64 blocks ----
        float* xl = smem;        // 256 floats
        float* wl = smem + 256;  // 3072 floats
        const int id = blockIdx.y * 2 + blockIdx.x;  // 0..63
        const int n = id >> 3;
        const int co0 = (id & 7) * 16;
        const int tid = threadIdx.x;
        {
            int ci = tid >> 2, y = tid & 3;
            xl[tid] = x[(((size_t)n * CIN + ci) * H + y) * W];
        }
        for (int p = tid; p < 16 * 192; p += 256) wl[p] = convw[co0 * 192 + p];
        __syncthreads();
        if (tid < 192) {
            int co = tid / 12, t = tid - co * 12;
            int r = t >> 2, y = t & 3;
            float s = 0.f;
#pragma unroll
            for (int ci = 0; ci < CIN; ++ci) s += wl[co * 192 + ci * 3 + r] * xl[ci * 4 + y];
            P[((size_t)n * COUT + co0 + co) * 16 + t] = s;
        }
        return;
    }

    // ---- offset conv ----
    const int n = blockIdx.z;
    const int i0 = blockIdx.y * TR;
    const int j0 = blockIdx.x * TC;
    const int tid = threadIdx.x;

    // staging constants: slot s = tid + 256k, k = 0..5 (k=5 only tid<80)
    int pw[6], boff[6];
    bool val[6], have[6];
#pragma unroll
    for (int k = 0; k < 6; ++k) {
        int s = tid + (k << 8);
        bool h = s < SLOTS_GRP;
        have[k] = h;
        int sc = h ? s : 0;
        int g = sc / SLOTS_PER;
        int s3 = sc - g * SLOTS_PER;
        int a = s3 / TCS;
        int c4 = s3 - a * TCS;
        int gi = i0 - 1 + a;
        int gj = j0 - 4 + (c4 << 2);
        bool v = h && ((unsigned)gi < (unsigned)H) && ((unsigned)gj <= 252u);
        val[k] = v;
        boff[k] = v ? (g * HW + gi * W + gj) : 0;
        pw[k] = g * TILEW + a * RSTRIDE + (c4 << 2);
    }

    const float* xn = x + (size_t)n * CIN * HW;
    const float4 zf4 = make_float4(0.f, 0.f, 0.f, 0.f);

    float4 RA0, RA1, RA2, RA3, RA4, RA5;
    RA0 = val[0] ? *(const float4*)(xn + boff[0]) : zf4;
    RA1 = val[1] ? *(const float4*)(xn + boff[1]) : zf4;
    RA2 = val[2] ? *(const float4*)(xn + boff[2]) : zf4;
    RA3 = val[3] ? *(const float4*)(xn + boff[3]) : zf4;
    RA4 = val[4] ? *(const float4*)(xn + boff[4]) : zf4;
    RA5 = val[5] ? *(const float4*)(xn + boff[5]) : zf4;

    float acc[3][4];
#pragma unroll
    for (int k = 0; k < 3; ++k)
#pragma unroll
        for (int d = 0; d < 4; ++d) acc[k][d] = 0.f;

    const int r = tid >> 5;   // output row 0..7
    const int qd = tid & 31;  // col quad 0..31

    for (int it = 0; it < 16; ++it) {
        float* buf = (it & 1) ? (smem + CPB * TILEW) : smem;
        // STAGE: consumes RA* (waits their vmcnt); invalid slots get zeros
        if (have[0]) *(float4*)(buf + pw[0]) = RA0;
        if (have[1]) *(float4*)(buf + pw[1]) = RA1;
        if (have[2]) *(float4*)(buf + pw[2]) = RA2;
        if (have[3]) *(float4*)(buf + pw[3]) = RA3;
        if (have[4]) *(float4*)(buf + pw[4]) = RA4;
        if (have[5]) *(float4*)(buf + pw[5]) = RA5;
        __syncthreads();
        __builtin_amdgcn_sched_barrier(0);  // keep next loads below the barrier
        if (it < 15) {
            const float* xc = xn + (size_t)((it + 1) * CPB) * HW;
            RA0 = val[0] ? *(const float4*)(xc + boff[0]) : zf4;
            RA1 = val[1] ? *(const float4*)(xc + boff[1]) : zf4;
            RA2 = val[2] ? *(const float4*)(xc + boff[2]) : zf4;
            RA3 = val[3] ? *(const float4*)(xc + boff[3]) : zf4;
            RA4 = val[4] ? *(const float4*)(xc + boff[4]) : zf4;
            RA5 = val[5] ? *(const float4*)(xc + boff[5]) : zf4;
        }
        // COMPUTE: 4 channels from buf
        const float* wpc = offw + (size_t)(it * CPB) * 9;
#pragma unroll
        for (int cc = 0; cc < CPB; ++cc) {
            const float* wp = wpc + cc * 9;  // offw[k][ci][u][v], k stride 576
            const float* tb = buf + cc * TILEW + r * RSTRIDE + (qd << 2);
#pragma unroll
            for (int u = 0; u < 3; ++u) {
                const float* rp = tb + u * RSTRIDE;
                float4 b1 = *(const float4*)(rp + 4);  // cols j..j+3
                float e0 = rp[3];                      // col j-1
                float e1 = rp[8];                      // col j+4
                const float r0 = e0, r1 = b1.x, r2 = b1.y, r3 = b1.z,
                            r4 = b1.w, r5 = e1;
#pragma unroll
                for (int kk = 0; kk < 3; ++kk) {
                    const float w0 = wp[kk * 576 + u * 3 + 0];
                    const float w1 = wp[kk * 576 + u * 3 + 1];
                    const float w2 = wp[kk * 576 + u * 3 + 2];
                    acc[kk][0] += r0 * w0 + r1 * w1 + r2 * w2;
                    acc[kk][1] += r1 * w0 + r2 * w1 + r3 * w2;
                    acc[kk][2] += r2 * w0 + r3 * w1 + r4 * w2;
                    acc[kk][3] += r3 * w0 + r4 * w1 + r5 * w2;
                }
            }
        }
    }

    // epilogue: tanh + cumsum combos, write ynew
    float y0[4], y1[4], y2[4];
#pragma unroll
    for (int d = 0; d < 4; ++d) {
        float t0 = tanhf(acc[0][d]);
        float t1 = tanhf(acc[1][d]);
        float t2 = tanhf(acc[2][d]);
        y0[d] = t0 + t1;
        y1[d] = t1;
        y2[d] = t1 + t2;
    }
    size_t base = (size_t)n * 3 * HW + (size_t)(i0 + r) * W + (j0 + (qd << 2));
    *(float4*)(ynew + base) = make_float4(y0[0], y0[1], y0[2], y0[3]);
    *(float4*)(ynew + base + (size_t)HW) = make_float4(y1[0], y1[1], y1[2], y1[3]);
    *(float4*)(ynew + base + (size_t)2 * HW) = make_float4(y2[0], y2[1], y2[2], y2[3]);
}

// ---------------------------------------------------------------------------
// Kernel C: out[n,co,i,j] = sum_t C[t](n,i,j) * P[n,co,t]  (unchanged, verified)
// ---------------------------------------------------------------------------
__global__ __launch_bounds__(256) void kout(const float* __restrict__ ynew,
                                            const float* __restrict__ P,
                                            float* __restrict__ out) {
    __shared__ float Cs[12 * 256];
    __shared__ float Pl[128 * 16];
    const int n = blockIdx.y;
    const int i = blockIdx.x;
    const int tid = threadIdx.x;

    {
        const f4v* src = (const f4v*)(P + (size_t)n * COUT * 16);
        f4v* dst = (f4v*)Pl;
        dst[tid] = src[tid];
        dst[tid + 256] = src[tid + 256];
    }

    {
        const int j = tid;
        float c[12];
#pragma unroll
        for (int t = 0; t < 12; ++t) c[t] = 0.f;
#pragma unroll
        for (int rr = 0; rr < 3; ++rr) {
            int rowi = 3 * i + rr;
            int k = rowi >> 8;
            int i2 = rowi & 255;
            float g = (float)(((k + i2 + j) % 3) - 1) +
                      ynew[((size_t)n * 3 + k) * (H * W) + i2 * W + j];
            float gy = g / 127.5f - 1.0f;
            float iy = ((gy + 1.0f) * 256.0f - 1.0f) * 0.5f;
            float fy = floorf(iy);
            int y0 = (int)fy;
            float w1 = iy - fy;
            if ((unsigned)y0 < 4u) c[rr * 4 + y0] += 0.5f * (1.0f - w1);
            int y1 = y0 + 1;
            if ((unsigned)y1 < 4u) c[rr * 4 + y1] += 0.5f * w1;
        }
#pragma unroll
        for (int t = 0; t < 12; ++t) Cs[t * 256 + j] = c[t];
    }
    __syncthreads();

    const int jq = (tid & 63) * 4;
    const int cg = tid >> 6;
    float4 cc[12];
#pragma unroll
    for (int t = 0; t < 12; ++t) cc[t] = *(const float4*)&Cs[t * 256 + jq];

    float* op = out + (((size_t)n * COUT) * H + i) * W;
    for (int co = cg * 32; co < cg * 32 + 32; ++co) {
        const float4* pp = (const float4*)&Pl[co * 16];
        float4 P0 = pp[0], P1 = pp[1], P2 = pp[2];
        float pv[12] = {P0.x, P0.y, P0.z, P0.w, P1.x, P1.y, P1.z, P1.w,
                        P2.x, P2.y, P2.z, P2.w};
        f4v a = {0.f, 0.f, 0.f, 0.f};
#pragma unroll
        for (int t = 0; t < 12; ++t) {
            a.x += pv[t] * cc[t].x;
            a.y += pv[t] * cc[t].y;
            a.z += pv[t] * cc[t].z;
            a.w += pv[t] * cc[t].w;
        }
        __builtin_nontemporal_store(a, (f4v*)(op + (size_t)co * (H * W) + jq));
    }
}

// ---------------------------------------------------------------------------
extern "C" void kernel_launch(void* const* d_in, const int* in_sizes, int n_in,
                              void* d_out, int out_size, void* d_ws, size_t ws_size,
                              hipStream_t stream) {
    const float* x = (const float*)d_in[0];      // [8,64,256,256]
    const float* offw = (const float*)d_in[1];   // [6,64,3,3]
    const float* convw = (const float*)d_in[2];  // [128,64,3,1]
    float* out = (float*)d_out;                  // [8,128,256,256]

    float* ynew = (float*)d_ws;                  // [8][3][256][256]
    float* P = ynew + (size_t)NB * 3 * HW;       // [8][128][16]

    // offset path: grid (2 jx, 32 iy, 8 n); kpmat plane at z==8 (2x32=64 blocks)
    kfused<<<dim3(2, 32, NB + 1), 256, 0, stream>>>(x, offw, convw, ynew, P);
    kout<<<dim3(H, NB), 256, 0, stream>>>(ynew, P, out);
}